// Round 6
// baseline (194.276 us; speedup 1.0000x reference)
//
#include <hip/hip_runtime.h>
#include <stdint.h>

typedef int v4i  __attribute__((ext_vector_type(4)));
typedef int v16i __attribute__((ext_vector_type(16)));

// Problem dims
#define N_IMG 32
#define C_IN 256
#define H_IN 56
#define W_IN 56
#define C_OUT 256
#define H_OUT 28
#define W_OUT 28
#define H_PAD 58
#define W_PAD 58
#define SP_TOT (N_IMG*H_OUT*W_OUT)   // 25088

#define XPAD_BYTES ((size_t)N_IMG*H_PAD*W_PAD*C_IN)   // 27,557,888 (16B aligned)

// NOTE: activations are stored in a PERMUTED channel order: stored position
// p holds original channel sigma(p) = 64*(p&3) + (p>>2). Weights use the
// same permutation on ci, so the conv's ci-sum is unchanged.

__device__ __forceinline__ void glds16(const int8_t* g, int8_t* l) {
    __builtin_amdgcn_global_load_lds(
        (const __attribute__((address_space(1))) void*)g,
        (__attribute__((address_space(3))) void*)l, 16, 0, 0);
}

// ---------------------------------------------------------------------------
// Kernel 1: quantize fp32 NCHW -> int8 NHWC' (permuted c), borders inline.
// [unchanged from R5 — runs concurrent with the harness's HBM-saturating
// ws-poison fill; see round-5 notes]
// ---------------------------------------------------------------------------
__global__ __launch_bounds__(256) void quant_kernel(const float* __restrict__ x,
                                                    int8_t* __restrict__ xpad) {
    __shared__ uint32_t ldsu[W_IN * 65];           // 14,560 B
    const int hp = blockIdx.x, n = blockIdx.y;     // hp-major dispatch
    const int t = threadIdx.x;
    int8_t* row = xpad + ((size_t)n * H_PAD + hp) * W_PAD * C_IN;

    if (hp == 0 || hp == H_PAD - 1) {
        // zero full padded row: 58*256 B = 928 x 16B
        #pragma unroll
        for (int i = 0; i < 4; ++i) {
            int idx = i * 256 + t;
            if (idx < 928) *(int4*)(row + idx * 16) = (int4){0, 0, 0, 0};
        }
        return;
    }
    const int h = hp - 1;
    const float* xp = x + (size_t)n * C_IN * H_IN * W_IN + (size_t)h * W_IN;

    const int wv = t >> 6, lane = t & 63;
    const int j = lane >> 4, w4 = lane & 15;
    const int w4c = (w4 < 14) ? w4 : 13;           // clamp; only store is masked
    const float* base = xp + (size_t)(64 * j) * (H_IN * W_IN) + w4c * 4;

    #pragma unroll
    for (int half = 0; half < 2; ++half) {
        // batch-issue 8 independent float4 loads (kept in flight together)
        float4 v[8];
        #pragma unroll
        for (int it = 0; it < 8; ++it) {
            const int c4 = (half * 8 + it) * 4 + wv;
            v[it] = *(const float4*)(base + (size_t)c4 * (H_IN * W_IN));
        }
        #pragma unroll
        for (int it = 0; it < 8; ++it) {
            const int c4 = (half * 8 + it) * 4 + wv;
            float f[4] = {v[it].x, v[it].y, v[it].z, v[it].w};
            uint32_t u = 0;
            #pragma unroll
            for (int i = 0; i < 4; ++i) {
                float qv = rintf(f[i] * 20.0f);     // ~= x/0.05, see notes
                qv = fminf(fmaxf(qv, -128.0f), 127.0f);
                u |= ((uint32_t)((int)qv & 255)) << (8 * i);  // byte i = w-offset i
            }
            // 4x4 byte transpose across lanes {j, same w4}
            uint32_t p1 = __shfl_xor(u, 16);
            uint32_t tt = (j & 1) ? (((p1 >> 8) & 0x00FF00FFu) | (u & 0xFF00FF00u))
                                  : ((u & 0x00FF00FFu) | ((p1 << 8) & 0xFF00FF00u));
            uint32_t p2 = __shfl_xor(tt, 32);
            uint32_t rr = (j & 2) ? ((p2 >> 16) | (tt & 0xFFFF0000u))
                                  : ((tt & 0x0000FFFFu) | (p2 << 16));
            // lane now holds w = 4*w4 + j, stored-channels 4*c4..4*c4+3
            if (w4 < 14) ldsu[(w4 * 4 + j) * 65 + c4] = rr;
        }
    }
    // zero border pixels w_p = 0 and w_p = 57 (32 x 16B), disjoint from Phase B
    if (t < 32) {
        int8_t* p = (t < 16) ? (row + t * 16)
                             : (row + (size_t)(W_PAD - 1) * C_IN + (t - 16) * 16);
        *(int4*)p = (int4){0, 0, 0, 0};
    }
    __syncthreads();

    // Phase B: write x_pad[n][hp][w+1][c'], 256B fully-coalesced per wave
    int8_t* op = row + C_IN;                    // w_p starts at 1
    #pragma unroll
    for (int it = 0; it < 14; ++it) {           // 56 w * 64 c4 = 3584
        int idx = it * 256 + t;
        int w = idx >> 6, c4 = idx & 63;
        *(uint32_t*)(op + (size_t)w * C_IN + c4 * 4) = ldsu[w * 65 + c4];
    }
}

// ---------------------------------------------------------------------------
// Kernel 2: repack weights fp32 [co][ci][kh][kw] -> int8 wq[khw][co][ci']
// with ci' permuted to match the activation layout: orig ci = 64*(p&3)+(p>>2)
// ---------------------------------------------------------------------------
__global__ __launch_bounds__(256) void wq_kernel(const float* __restrict__ w,
                                                 int8_t* __restrict__ wq) {
    int idx = blockIdx.x * 256 + threadIdx.x;   // < 9*256*256 = 589824
    int p   = idx & 255;
    int co  = (idx >> 8) & 255;
    int khw = idx >> 16;
    int ci  = 64 * (p & 3) + (p >> 2);          // sigma(p)
    float v = w[(size_t)(co * C_IN + ci) * 9 + khw];
    wq[idx] = (int8_t)(int)rintf(v);
}

// ---------------------------------------------------------------------------
// Kernel 3: implicit-GEMM conv via v_mfma_i32_32x32x32_i8.
// Block 256 thr = 4 waves; block tile 128co x 64sp; wave tile 64co x 32sp
// (2 x v16i acc). Grid 392 x 2 = 784 blocks; LDS 48KB -> 3 blocks/CU.
// 9 stages (one 3x3 tap, BK=256): stage = 12 glds16/thread (W 32KB + A 16KB),
// XOR chunk swizzle (rows 16-aligned => swizzle term = l31&15, conflict-free);
// per wave per stage: 24 ds_read_b128 + 16 MFMA.
// A-op: m(co)=lane&31, k-bytes=(lane>>5)*16. B-op: n(sp)=lane&31, same k.
// C/D: col(sp)=lane&31, row(co)=(reg&3)+8*(reg>>2)+4*(lane>>5)  [m74/m101]
// ---------------------------------------------------------------------------
__global__ __launch_bounds__(256) void conv_kernel(const int8_t* __restrict__ xpad,
                                                   const int8_t* __restrict__ wq,
                                                   float* __restrict__ out) {
    __shared__ __align__(16) int8_t lds[49152];  // W: [0,32768) Act: [32768,49152)
    const int t = threadIdx.x;
    const int wave = t >> 6, lane = t & 63;
    const int l31 = lane & 31, khalf = lane >> 5;
    const int co_blk = blockIdx.y * 128;
    const int sp_blk = blockIdx.x * 64;

    // ---- staging decode (fixed per thread) ----
    const int rl    = t >> 4;                     // row_l for pass r=0 (0..15)
    const int chunk = (t & 15) ^ (rl & 15);
    const int8_t* gw = wq + (size_t)(co_blk + rl) * 256 + chunk * 16; // +r*4096 +tap*65536

    const int8_t* ga[4];
    #pragma unroll
    for (int r = 0; r < 4; ++r) {
        int sp = sp_blk + r * 16 + rl;
        int n  = sp / (H_OUT * W_OUT);
        int rm = sp - n * (H_OUT * W_OUT);
        int ho = rm / W_OUT;
        int wo = rm - ho * W_OUT;
        ga[r] = xpad + ((size_t)(n * H_PAD + ho * 2) * W_PAD + wo * 2) * C_IN + chunk * 16;
    }

    // ---- output mapping (one sp per thread; both accs share it) ----
    const int cw = (wave >> 1) * 64;          // wave co base within block
    const int sw = (wave & 1) * 32;           // wave sp base within block
    {
    }
    const int spo = sp_blk + sw + l31;
    const int no  = spo / (H_OUT * W_OUT);
    const int rmo = spo - no * (H_OUT * W_OUT);
    const int hoo = rmo / W_OUT;
    const int woo = rmo - hoo * W_OUT;
    float* outp = out + (size_t)no * (C_OUT * H_OUT * W_OUT) + hoo * W_OUT + woo
                      + (size_t)(co_blk + cw + 4 * khalf) * (H_OUT * W_OUT);

    v16i acc[2];
    #pragma unroll
    for (int i = 0; i < 2; ++i)
        #pragma unroll
        for (int r = 0; r < 16; ++r)
            acc[i][r] = 0;

    const int swz = (l31 & 15);               // XOR swizzle term for ds_reads

    // ---- K loop: 9 stages (one tap each) ----
    for (int kh = 0; kh < 3; ++kh) {
        for (int kwv = 0; kwv < 3; ++kwv) {
            __syncthreads();                       // all waves done reading prev stage
            const int woff = (kh * 3 + kwv) * (C_OUT * C_IN);
            const int aoff = (kh * W_PAD + kwv) * C_IN;
            #pragma unroll
            for (int r = 0; r < 8; ++r)            // W: 128 rows x 256B = 32KB
                glds16(gw + woff + r * 4096, lds + r * 4096 + t * 16);
            #pragma unroll
            for (int r = 0; r < 4; ++r)            // Act: 64 rows x 256B = 16KB
                glds16(ga[r] + aoff, lds + 32768 + r * 4096 + t * 16);
            __syncthreads();                       // vmcnt(0) drain: LDS ready

            #pragma unroll
            for (int ks = 0; ks < 8; ++ks) {       // k = 32 bytes per step
                const int st = ((2 * ks + khalf) ^ swz) * 16;   // swizzled chunk
                v4i b = *(const v4i*)(lds + 32768 + (sw + l31) * 256 + st);
                #pragma unroll
                for (int i = 0; i < 2; ++i) {
                    v4i a = *(const v4i*)(lds + (cw + 32 * i + l31) * 256 + st);
                    acc[i] = __builtin_amdgcn_mfma_i32_32x32x32_i8(a, b, acc[i], 0, 0, 0);
                }
            }
        }
    }

    // ---- epilogue: 32 coalesced dword stores (lanes 0-31 = consecutive sp) ----
    #pragma unroll
    for (int i = 0; i < 2; ++i) {
        #pragma unroll
        for (int r = 0; r < 16; ++r) {
            const int cof = 32 * i + (r & 3) + 8 * (r >> 2);   // co offset from cw+4*khalf
            outp[(size_t)cof * (H_OUT * W_OUT)] = (float)acc[i][r] * 0.0005f;
        }
    }
}

// ---------------------------------------------------------------------------
extern "C" void kernel_launch(void* const* d_in, const int* in_sizes, int n_in,
                              void* d_out, int out_size, void* d_ws, size_t ws_size,
                              hipStream_t stream) {
    const float* x = (const float*)d_in[0];
    const float* w = (const float*)d_in[1];
    float* out = (float*)d_out;
    int8_t* xpad = (int8_t*)d_ws;
    int8_t* wqb  = xpad + XPAD_BYTES;

    quant_kernel<<<dim3(H_PAD, N_IMG), 256, 0, stream>>>(x, xpad);
    wq_kernel<<<(9 * C_OUT * C_IN) / 256, 256, 0, stream>>>(w, wqb);
    conv_kernel<<<dim3(SP_TOT / 64, C_OUT / 128), 256, 0, stream>>>(xpad, wqb, out);
}